// Round 1
// baseline (1547.303 us; speedup 1.0000x reference)
//
#include <hip/hip_runtime.h>
#include <hip/hip_bf16.h>

// Problem constants (Qwen3MoeAttention: T=16384, HIDDEN=4096, TOTAL=5120)
#define T_TOK   16384
#define HID     4096
#define NTOT    5120          // Q_HID(4096) + KV_HID(512) + KV_HID(512)
#define Q_HID   4096
#define KV_END  4608          // Q_HID + KV_HID
#define HD      128           // head dim
#define EPSV    1e-6f

typedef __bf16 bf16x8 __attribute__((ext_vector_type(8)));
typedef float  f32x4  __attribute__((ext_vector_type(4)));

// ---------------------------------------------------------------------------
// fp32 -> bf16 (round-to-nearest-even), float4 in / ushort4 out (memory-bound)
// ---------------------------------------------------------------------------
__device__ __forceinline__ unsigned short f2bf(float f) {
    unsigned u = __builtin_bit_cast(unsigned, f);
    u += 0x7fffu + ((u >> 16) & 1u);          // RNE (inputs finite, no NaN care)
    return (unsigned short)(u >> 16);
}

__global__ void cvt_bf16(const float* __restrict__ in,
                         unsigned short* __restrict__ out, long n) {
    long i = 4L * (blockIdx.x * (long)blockDim.x + threadIdx.x);
    if (i >= n) return;
    float4 v = *reinterpret_cast<const float4*>(in + i);
    ushort4 o;
    o.x = f2bf(v.x); o.y = f2bf(v.y); o.z = f2bf(v.z); o.w = f2bf(v.w);
    *reinterpret_cast<ushort4*>(out + i) = o;
}

// ---------------------------------------------------------------------------
// Fused GEMM (C = A * W^T, both K-contiguous) + per-head RMSNorm + RoPE
// Block: 256 threads = 4 waves, tile 128(M) x 128(N), BK=32.
// Wave w owns rows w*32..w*32+31, all 128 cols: 2(tm) x 8(tn) MFMA 16x16x32.
// ---------------------------------------------------------------------------
#define BM 128
#define BN 128
#define BK 32

__global__ __launch_bounds__(256)
void gemm_rmsnorm_rope(const unsigned short* __restrict__ A,   // T x HID bf16
                       const unsigned short* __restrict__ B,   // NTOT x HID bf16
                       const float* __restrict__ sinp,         // T x 128
                       const float* __restrict__ cosp,         // T x 128
                       const float* __restrict__ qw,           // 128
                       const float* __restrict__ kw,           // 128
                       float* __restrict__ out)                // T x NTOT
{
    __shared__ unsigned short sA[BM * BK];   // 8192 B, row-major, 64 B/row
    __shared__ unsigned short sB[BN * BK];   // 8192 B

    const int tid  = threadIdx.x;
    const int wave = tid >> 6;
    const int lane = tid & 63;
    const int l15  = lane & 15;
    const int quad = lane >> 4;

    const int m0 = blockIdx.y * BM;
    const int n0 = blockIdx.x * BN;

    const unsigned short* Ab = A + (size_t)m0 * HID;
    const unsigned short* Bb = B + (size_t)n0 * HID;

    f32x4 acc[2][8];
    const f32x4 zero = {0.f, 0.f, 0.f, 0.f};
#pragma unroll
    for (int tm = 0; tm < 2; ++tm)
#pragma unroll
        for (int tn = 0; tn < 8; ++tn) acc[tm][tn] = zero;

    // Per-lane LDS frag addresses (constant across K iterations)
    const unsigned short* aAddr[2];
    const unsigned short* bAddr[8];
#pragma unroll
    for (int tm = 0; tm < 2; ++tm)
        aAddr[tm] = sA + (wave * 32 + tm * 16 + l15) * BK + quad * 8;
#pragma unroll
    for (int tn = 0; tn < 8; ++tn)
        bAddr[tn] = sB + (tn * 16 + l15) * BK + quad * 8;

    for (int k0 = 0; k0 < HID; k0 += BK) {
        __syncthreads();   // all waves done reading previous tile
        // Stage A and B tiles: 512 x 16B chunks each, 256 threads, 2 iters.
        // chunk = tid + it*256; LDS dest = chunk*16 B  (wave-uniform base +
        // lane*16 within each wave -> satisfies global_load_lds constraint)
#pragma unroll
        for (int it = 0; it < 2; ++it) {
            const int chunk = tid + it * 256;
            const int row = chunk >> 2;          // 0..127
            const int kp  = chunk & 3;           // 16B piece within 64B row
            const unsigned short* gA = Ab + (size_t)row * HID + k0 + kp * 8;
            const unsigned short* gB = Bb + (size_t)row * HID + k0 + kp * 8;
            __builtin_amdgcn_global_load_lds(
                (const __attribute__((address_space(1))) void*)gA,
                (__attribute__((address_space(3))) void*)(sA + chunk * 8),
                16, 0, 0);
            __builtin_amdgcn_global_load_lds(
                (const __attribute__((address_space(1))) void*)gB,
                (__attribute__((address_space(3))) void*)(sB + chunk * 8),
                16, 0, 0);
        }
        __syncthreads();   // drains vmcnt (compiler inserts waitcnt) + barrier

        bf16x8 af[2], bf[8];
#pragma unroll
        for (int tm = 0; tm < 2; ++tm)
            af[tm] = *reinterpret_cast<const bf16x8*>(aAddr[tm]);
#pragma unroll
        for (int tn = 0; tn < 8; ++tn)
            bf[tn] = *reinterpret_cast<const bf16x8*>(bAddr[tn]);

#pragma unroll
        for (int tm = 0; tm < 2; ++tm)
#pragma unroll
            for (int tn = 0; tn < 8; ++tn)
                acc[tm][tn] = __builtin_amdgcn_mfma_f32_16x16x32_bf16(
                    af[tm], bf[tn], acc[tm][tn], 0, 0, 0);
    }

    // ---------------- fused epilogue ----------------
    // C/D layout (m89-verified): col = lane&15, row = quad*4 + reg.
    // Wave rows: m0 + wave*32 + tm*16 + quad*4 + r ; cols: tn*16 + l15.
    // RoPE partner col c+64 = same lane, tn+4. RMS sum: 8 local sq + 4 shfl_xor.
    if (n0 >= KV_END) {
        // V tiles: passthrough store
#pragma unroll
        for (int tm = 0; tm < 2; ++tm)
#pragma unroll
            for (int r = 0; r < 4; ++r) {
                const int row = m0 + wave * 32 + tm * 16 + quad * 4 + r;
                float* orow = out + (size_t)row * NTOT + n0;
#pragma unroll
                for (int tn = 0; tn < 8; ++tn)
                    orow[tn * 16 + l15] = acc[tm][tn][r];
            }
    } else {
        const float* w = (n0 < Q_HID) ? qw : kw;
        float wv[8];
#pragma unroll
        for (int tn = 0; tn < 8; ++tn) wv[tn] = w[tn * 16 + l15];

#pragma unroll
        for (int tm = 0; tm < 2; ++tm)
#pragma unroll
            for (int r = 0; r < 4; ++r) {
                const int row = m0 + wave * 32 + tm * 16 + quad * 4 + r;
                float ss = 0.f;
#pragma unroll
                for (int tn = 0; tn < 8; ++tn) {
                    const float v = acc[tm][tn][r];
                    ss += v * v;
                }
                ss += __shfl_xor(ss, 1);
                ss += __shfl_xor(ss, 2);
                ss += __shfl_xor(ss, 4);
                ss += __shfl_xor(ss, 8);
                const float scale = rsqrtf(ss * (1.0f / 128.0f) + EPSV);

                float xn[8];
#pragma unroll
                for (int tn = 0; tn < 8; ++tn)
                    xn[tn] = acc[tm][tn][r] * scale * wv[tn];

                const float* srow = sinp + (size_t)row * HD;
                const float* crow = cosp + (size_t)row * HD;
                float* orow = out + (size_t)row * NTOT + n0;
#pragma unroll
                for (int tn = 0; tn < 4; ++tn) {
                    const int c = tn * 16 + l15;
                    const float sv = srow[c];   // sin[c]==sin[c+64]
                    const float cv = crow[c];   // cos[c]==cos[c+64]
                    orow[c]      = xn[tn] * cv - xn[tn + 4] * sv;
                    orow[c + 64] = xn[tn] * sv + xn[tn + 4] * cv;
                }
            }
    }
}

// ---------------------------------------------------------------------------
extern "C" void kernel_launch(void* const* d_in, const int* in_sizes, int n_in,
                              void* d_out, int out_size, void* d_ws, size_t ws_size,
                              hipStream_t stream) {
    const float* hidden = (const float*)d_in[0];   // T x HID
    const float* sinp   = (const float*)d_in[1];   // T x 128
    const float* cosp   = (const float*)d_in[2];   // T x 128
    const float* w_qkv  = (const float*)d_in[3];   // NTOT x HID
    const float* qnw    = (const float*)d_in[4];   // 128
    const float* knw    = (const float*)d_in[5];   // 128
    float* out = (float*)d_out;

    // Workspace: bf16 copies of A (T x HID) then B (NTOT x HID). 176 MB total.
    unsigned short* Abf = (unsigned short*)d_ws;
    unsigned short* Bbf = Abf + (size_t)T_TOK * HID;

    const long nA = (long)T_TOK * HID;     // 67,108,864
    const long nB = (long)NTOT * HID;      // 20,971,520
    cvt_bf16<<<(unsigned)(nA / 4 / 256), 256, 0, stream>>>(hidden, Abf, nA);
    cvt_bf16<<<(unsigned)(nB / 4 / 256), 256, 0, stream>>>(w_qkv, Bbf, nB);

    dim3 grid(NTOT / BN, T_TOK / BM);      // (40, 128)
    gemm_rmsnorm_rope<<<grid, 256, 0, stream>>>(Abf, Bbf, sinp, cosp, qnw, knw, out);
}